// Round 1
// baseline (284.402 us; speedup 1.0000x reference)
//
#include <hip/hip_runtime.h>
#include <math.h>

#define BB 64
#define LL 200
#define DD 128
#define MM 50
#define NQ 10000
#define NPOS (BB * LL)   // 12800

// ---------------------------------------------------------------------------
// Kernel 1: gather k,v; compute w = softmax(k@Mk^T), e = sigmoid(v@e_W^T+e_b),
//           a = tanh(v@a_W^T+a_b) for all B*L positions.
// One block = 16 positions, 256 threads.
// ---------------------------------------------------------------------------
__global__ __launch_bounds__(256) void k_wea(
    const int* __restrict__ q, const int* __restrict__ r,
    const float* __restrict__ k_emb, const float* __restrict__ v_emb,
    const float* __restrict__ Mk,
    const float* __restrict__ e_W, const float* __restrict__ e_b,
    const float* __restrict__ a_W, const float* __restrict__ a_b,
    float* __restrict__ w_ws, float* __restrict__ e_ws, float* __restrict__ a_ws)
{
    __shared__ float k_lds[16][DD];
    __shared__ float v_lds[16][DD];
    __shared__ float lg[16][MM];

    const int tid = threadIdx.x;
    const int p0  = blockIdx.x * 16;

    // ---- stage k, v rows into LDS (float4-coalesced) ----
    #pragma unroll
    for (int rep = 0; rep < 2; ++rep) {
        int idx = rep * 256 + tid;        // 0..511
        int pos = idx >> 5;               // 16 positions x 32 float4
        int c4  = idx & 31;
        int gp  = p0 + pos;
        int qi  = q[gp];
        int xi  = qi + NQ * r[gp];
        float4 kv = *(const float4*)(k_emb + (size_t)qi * DD + c4 * 4);
        float4 vv = *(const float4*)(v_emb + (size_t)xi * DD + c4 * 4);
        *(float4*)(&k_lds[pos][c4 * 4]) = kv;
        *(float4*)(&v_lds[pos][c4 * 4]) = vv;
    }
    __syncthreads();

    // ---- logits: 16 pos x 50 m dots of length 128 ----
    for (int j = tid; j < 16 * MM; j += 256) {
        int pos = j / MM;
        int m   = j - pos * MM;
        const float* mk = Mk + m * DD;
        float acc = 0.f;
        #pragma unroll 4
        for (int jj = 0; jj < DD; ++jj)
            acc = fmaf(k_lds[pos][jj], mk[jj], acc);
        lg[pos][m] = acc;
    }
    __syncthreads();

    // ---- softmax over M=50, one thread per position ----
    if (tid < 16) {
        int pos = tid;
        float mx = -INFINITY;
        for (int m = 0; m < MM; ++m) mx = fmaxf(mx, lg[pos][m]);
        float s = 0.f;
        for (int m = 0; m < MM; ++m) {
            float e_ = expf(lg[pos][m] - mx);
            lg[pos][m] = e_;
            s += e_;
        }
        float inv = 1.f / s;
        float* wout = w_ws + (size_t)(p0 + pos) * MM;
        for (int m = 0; m < MM; ++m) wout[m] = lg[pos][m] * inv;
    }

    // ---- e, a: thread (i = tid&127) x (half = tid>>7 -> 8 positions) ----
    const int i    = tid & 127;
    const int half = tid >> 7;
    float acc_e[8], acc_a[8];
    const float eb = e_b[i];
    const float ab = a_b[i];
    #pragma unroll
    for (int p = 0; p < 8; ++p) { acc_e[p] = eb; acc_a[p] = ab; }

    const float4* ew = (const float4*)(e_W + (size_t)i * DD);
    const float4* aw = (const float4*)(a_W + (size_t)i * DD);
    #pragma unroll 4
    for (int j4 = 0; j4 < 32; ++j4) {
        float4 we = ew[j4];
        float4 wa = aw[j4];
        #pragma unroll
        for (int p = 0; p < 8; ++p) {
            const float* vp = &v_lds[half * 8 + p][j4 * 4];
            acc_e[p] = fmaf(we.x, vp[0], acc_e[p]);
            acc_e[p] = fmaf(we.y, vp[1], acc_e[p]);
            acc_e[p] = fmaf(we.z, vp[2], acc_e[p]);
            acc_e[p] = fmaf(we.w, vp[3], acc_e[p]);
            acc_a[p] = fmaf(wa.x, vp[0], acc_a[p]);
            acc_a[p] = fmaf(wa.y, vp[1], acc_a[p]);
            acc_a[p] = fmaf(wa.z, vp[2], acc_a[p]);
            acc_a[p] = fmaf(wa.w, vp[3], acc_a[p]);
        }
    }
    #pragma unroll
    for (int p = 0; p < 8; ++p) {
        int gp = p0 + half * 8 + p;
        e_ws[(size_t)gp * DD + i] = 1.f / (1.f + expf(-acc_e[p]));
        a_ws[(size_t)gp * DD + i] = tanhf(acc_a[p]);
    }
}

// ---------------------------------------------------------------------------
// Kernel 2: sequential scan over L. One block = (b, 64-column chunk of D).
// State Mv[50] per thread (its column). Writes all Mv states (incl. init)
// and read[b,l,d] = sum_m w*Mv_pre.
// ---------------------------------------------------------------------------
__global__ __launch_bounds__(64) void k_scan(
    const float* __restrict__ Mv0,
    const float* __restrict__ w_ws, const float* __restrict__ e_ws,
    const float* __restrict__ a_ws, float* __restrict__ read_ws,
    float* __restrict__ out_Mv)
{
    const int b = blockIdx.x >> 1;
    const int d = ((blockIdx.x & 1) << 6) | threadIdx.x;

    float S[MM];
    float* outb = out_Mv + (size_t)b * (LL + 1) * MM * DD;
    #pragma unroll
    for (int m = 0; m < MM; ++m) {
        S[m] = Mv0[m * DD + d];
        outb[m * DD + d] = S[m];   // Mv state at l=0 (initial)
    }

    for (int l = 0; l < LL; ++l) {
        const int gp = b * LL + l;
        const float e = e_ws[(size_t)gp * DD + d];
        const float a = a_ws[(size_t)gp * DD + d];
        float w[MM];
        const float* wp = w_ws + (size_t)gp * MM;
        #pragma unroll
        for (int m = 0; m < MM; ++m) w[m] = wp[m];

        float racc = 0.f;
        float* o = outb + (size_t)(l + 1) * MM * DD + d;
        #pragma unroll
        for (int m = 0; m < MM; ++m) {
            racc = fmaf(w[m], S[m], racc);              // read uses pre-update state
            S[m] = fmaf(w[m], fmaf(-S[m], e, a), S[m]); // S += w*(a - S*e)
            o[m * DD] = S[m];
        }
        read_ws[(size_t)gp * DD + d] = racc;
    }
}

// ---------------------------------------------------------------------------
// Kernel 3: f = tanh([read,k] @ f_W^T + f_b); p = sigmoid(f . p_W + p_b).
// One block = 16 positions, 128 threads.
// ---------------------------------------------------------------------------
__global__ __launch_bounds__(128) void k_fp(
    const int* __restrict__ q,
    const float* __restrict__ k_emb,
    const float* __restrict__ read_ws,
    const float* __restrict__ f_W, const float* __restrict__ f_b,
    const float* __restrict__ p_W, const float* __restrict__ p_b,
    float* __restrict__ out_p)
{
    __shared__ float cat[16][2 * DD];
    __shared__ float fv[16][DD];

    const int tid = threadIdx.x;
    const int p0  = blockIdx.x * 16;

    // stage [read, k] rows (256 floats each) into LDS
    #pragma unroll
    for (int rep = 0; rep < 8; ++rep) {
        int idx = rep * 128 + tid;        // 0..1023 = 16 pos x 64 float4
        int pos = idx >> 6;
        int c4  = idx & 63;
        int gp  = p0 + pos;
        float4 val;
        if (c4 < 32) val = *(const float4*)(read_ws + (size_t)gp * DD + c4 * 4);
        else         val = *(const float4*)(k_emb + (size_t)q[gp] * DD + (c4 - 32) * 4);
        *(float4*)(&cat[pos][c4 * 4]) = val;
    }
    __syncthreads();

    // f: thread i computes f[pos][i] for all 16 positions
    const int i = tid;
    float acc[16];
    const float fb = f_b[i];
    #pragma unroll
    for (int p = 0; p < 16; ++p) acc[p] = fb;

    const float4* fw = (const float4*)(f_W + (size_t)i * (2 * DD));
    #pragma unroll 2
    for (int j4 = 0; j4 < 64; ++j4) {
        float4 wv = fw[j4];
        #pragma unroll
        for (int p = 0; p < 16; ++p) {
            const float* cp = &cat[p][j4 * 4];
            acc[p] = fmaf(wv.x, cp[0], acc[p]);
            acc[p] = fmaf(wv.y, cp[1], acc[p]);
            acc[p] = fmaf(wv.z, cp[2], acc[p]);
            acc[p] = fmaf(wv.w, cp[3], acc[p]);
        }
    }
    #pragma unroll
    for (int p = 0; p < 16; ++p) fv[p][i] = tanhf(acc[p]);
    __syncthreads();

    // p: 16 positions x 8 lanes each
    const int pos = tid >> 3;
    const int l8  = tid & 7;
    float partial = 0.f;
    #pragma unroll
    for (int ii = l8; ii < DD; ii += 8)
        partial = fmaf(fv[pos][ii], p_W[ii], partial);
    partial += __shfl_down(partial, 4, 64);
    partial += __shfl_down(partial, 2, 64);
    partial += __shfl_down(partial, 1, 64);
    if (l8 == 0)
        out_p[p0 + pos] = 1.f / (1.f + expf(-(partial + p_b[0])));
}

// ---------------------------------------------------------------------------
extern "C" void kernel_launch(void* const* d_in, const int* in_sizes, int n_in,
                              void* d_out, int out_size, void* d_ws, size_t ws_size,
                              hipStream_t stream)
{
    const int*   q     = (const int*)d_in[0];
    const int*   r     = (const int*)d_in[1];
    const float* k_emb = (const float*)d_in[2];
    const float* v_emb = (const float*)d_in[3];
    const float* Mk    = (const float*)d_in[4];
    const float* Mv0   = (const float*)d_in[5];
    const float* f_W   = (const float*)d_in[6];
    const float* f_b   = (const float*)d_in[7];
    const float* p_W   = (const float*)d_in[8];
    const float* p_b   = (const float*)d_in[9];
    const float* e_W   = (const float*)d_in[10];
    const float* e_b   = (const float*)d_in[11];
    const float* a_W   = (const float*)d_in[12];
    const float* a_b   = (const float*)d_in[13];

    float* out_p  = (float*)d_out;           // [B,L]
    float* out_Mv = out_p + NPOS;            // [B,L+1,M,D]

    float* w_ws    = (float*)d_ws;                         // NPOS*MM
    float* e_ws    = w_ws + (size_t)NPOS * MM;             // NPOS*DD
    float* a_ws    = e_ws + (size_t)NPOS * DD;             // NPOS*DD
    float* read_ws = a_ws + (size_t)NPOS * DD;             // NPOS*DD

    hipLaunchKernelGGL(k_wea, dim3(NPOS / 16), dim3(256), 0, stream,
                       q, r, k_emb, v_emb, Mk, e_W, e_b, a_W, a_b,
                       w_ws, e_ws, a_ws);
    hipLaunchKernelGGL(k_scan, dim3(BB * 2), dim3(64), 0, stream,
                       Mv0, w_ws, e_ws, a_ws, read_ws, out_Mv);
    hipLaunchKernelGGL(k_fp, dim3(NPOS / 16), dim3(128), 0, stream,
                       q, k_emb, read_ws, f_W, f_b, p_W, p_b, out_p);
}

// Round 2
// 224.557 us; speedup vs baseline: 1.2665x; 1.2665x over previous
//
#include <hip/hip_runtime.h>
#include <math.h>

#define BB 64
#define LL 200
#define DD 128
#define MM 50
#define NQ 10000
#define NPOS (BB * LL)   // 12800
#define LC 20            // scan chunk length
#define NC 10            // number of chunks (LC*NC == LL)

// ---------------------------------------------------------------------------
// Kernel 1: gather k,v; compute w = softmax(k@Mk^T), e = sigmoid(v@e_W^T+e_b),
//           a = tanh(v@a_W^T+a_b) for all B*L positions.
// One block = 16 positions, 256 threads.
// ---------------------------------------------------------------------------
__global__ __launch_bounds__(256) void k_wea(
    const int* __restrict__ q, const int* __restrict__ r,
    const float* __restrict__ k_emb, const float* __restrict__ v_emb,
    const float* __restrict__ Mk,
    const float* __restrict__ e_W, const float* __restrict__ e_b,
    const float* __restrict__ a_W, const float* __restrict__ a_b,
    float* __restrict__ w_ws, float* __restrict__ e_ws, float* __restrict__ a_ws)
{
    __shared__ float k_lds[16][DD];
    __shared__ float v_lds[16][DD];
    __shared__ float lg[16][MM];

    const int tid = threadIdx.x;
    const int p0  = blockIdx.x * 16;

    // ---- stage k, v rows into LDS (float4-coalesced) ----
    #pragma unroll
    for (int rep = 0; rep < 2; ++rep) {
        int idx = rep * 256 + tid;        // 0..511
        int pos = idx >> 5;               // 16 positions x 32 float4
        int c4  = idx & 31;
        int gp  = p0 + pos;
        int qi  = q[gp];
        int xi  = qi + NQ * r[gp];
        float4 kv = *(const float4*)(k_emb + (size_t)qi * DD + c4 * 4);
        float4 vv = *(const float4*)(v_emb + (size_t)xi * DD + c4 * 4);
        *(float4*)(&k_lds[pos][c4 * 4]) = kv;
        *(float4*)(&v_lds[pos][c4 * 4]) = vv;
    }
    __syncthreads();

    // ---- logits: 16 pos x 50 m dots of length 128 ----
    for (int j = tid; j < 16 * MM; j += 256) {
        int pos = j / MM;
        int m   = j - pos * MM;
        const float* mk = Mk + m * DD;
        float acc = 0.f;
        #pragma unroll 4
        for (int jj = 0; jj < DD; ++jj)
            acc = fmaf(k_lds[pos][jj], mk[jj], acc);
        lg[pos][m] = acc;
    }
    __syncthreads();

    // ---- softmax over M=50, one thread per position ----
    if (tid < 16) {
        int pos = tid;
        float mx = -INFINITY;
        for (int m = 0; m < MM; ++m) mx = fmaxf(mx, lg[pos][m]);
        float s = 0.f;
        for (int m = 0; m < MM; ++m) {
            float e_ = expf(lg[pos][m] - mx);
            lg[pos][m] = e_;
            s += e_;
        }
        float inv = 1.f / s;
        float* wout = w_ws + (size_t)(p0 + pos) * MM;
        for (int m = 0; m < MM; ++m) wout[m] = lg[pos][m] * inv;
    }

    // ---- e, a: thread (i = tid&127) x (half = tid>>7 -> 8 positions) ----
    const int i    = tid & 127;
    const int half = tid >> 7;
    float acc_e[8], acc_a[8];
    const float eb = e_b[i];
    const float ab = a_b[i];
    #pragma unroll
    for (int p = 0; p < 8; ++p) { acc_e[p] = eb; acc_a[p] = ab; }

    const float4* ew = (const float4*)(e_W + (size_t)i * DD);
    const float4* aw = (const float4*)(a_W + (size_t)i * DD);
    #pragma unroll 4
    for (int j4 = 0; j4 < 32; ++j4) {
        float4 we = ew[j4];
        float4 wa = aw[j4];
        #pragma unroll
        for (int p = 0; p < 8; ++p) {
            const float* vp = &v_lds[half * 8 + p][j4 * 4];
            acc_e[p] = fmaf(we.x, vp[0], acc_e[p]);
            acc_e[p] = fmaf(we.y, vp[1], acc_e[p]);
            acc_e[p] = fmaf(we.z, vp[2], acc_e[p]);
            acc_e[p] = fmaf(we.w, vp[3], acc_e[p]);
            acc_a[p] = fmaf(wa.x, vp[0], acc_a[p]);
            acc_a[p] = fmaf(wa.y, vp[1], acc_a[p]);
            acc_a[p] = fmaf(wa.z, vp[2], acc_a[p]);
            acc_a[p] = fmaf(wa.w, vp[3], acc_a[p]);
        }
    }
    #pragma unroll
    for (int p = 0; p < 8; ++p) {
        int gp = p0 + half * 8 + p;
        e_ws[(size_t)gp * DD + i] = 1.f / (1.f + expf(-acc_e[p]));
        a_ws[(size_t)gp * DD + i] = tanhf(acc_a[p]);
    }
}

// ---------------------------------------------------------------------------
// Kernel 2a: per (b, chunk) affine composite of the scan:
//   S_out = A*S_in + B over the chunk, per (m,d).
// ---------------------------------------------------------------------------
__global__ __launch_bounds__(128) void k_scanA(
    const float* __restrict__ w_ws, const float* __restrict__ e_ws,
    const float* __restrict__ a_ws,
    float* __restrict__ A_ws, float* __restrict__ B_ws)
{
    const int b = blockIdx.x / NC;
    const int c = blockIdx.x % NC;
    const int d = threadIdx.x;

    float A[MM], Bv[MM];
    #pragma unroll
    for (int m = 0; m < MM; ++m) { A[m] = 1.f; Bv[m] = 0.f; }

    for (int l = c * LC; l < c * LC + LC; ++l) {
        const int gp = b * LL + l;
        const float e = e_ws[(size_t)gp * DD + d];
        const float a = a_ws[(size_t)gp * DD + d];
        const float* wp = w_ws + (size_t)gp * MM;
        float w_[MM];
        #pragma unroll
        for (int m = 0; m < MM; ++m) w_[m] = wp[m];
        #pragma unroll
        for (int m = 0; m < MM; ++m) {
            float cc = fmaf(-w_[m], e, 1.f);
            A[m] *= cc;
            Bv[m] = fmaf(Bv[m], cc, w_[m] * a);
        }
    }

    float* Ao = A_ws + ((size_t)b * NC + c) * MM * DD + d;
    float* Bo = B_ws + ((size_t)b * NC + c) * MM * DD + d;
    #pragma unroll
    for (int m = 0; m < MM; ++m) { Ao[m * DD] = A[m]; Bo[m * DD] = Bv[m]; }
}

// ---------------------------------------------------------------------------
// Kernel 2b: sequential composition over chunks; writes chunk ENTRY states
// in-place over A_ws. One thread per (b,m,d).
// ---------------------------------------------------------------------------
__global__ __launch_bounds__(256) void k_scanB(
    const float* __restrict__ Mv0,
    float* __restrict__ A_ws,            // in: A, out: Sentry
    const float* __restrict__ B_ws)
{
    const int g  = blockIdx.x * 256 + threadIdx.x;   // 0 .. B*M*D-1
    const int d  = g & (DD - 1);
    const int md = g >> 7;
    const int m  = md % MM;
    const int b  = md / MM;

    float S = Mv0[m * DD + d];
    const size_t base = ((size_t)b * NC * MM + m) * DD + d;  // +c*MM*DD per chunk
    #pragma unroll
    for (int c = 0; c < NC; ++c) {
        const size_t off = base + (size_t)c * MM * DD;
        const float Ac = A_ws[off];
        const float Bc = B_ws[off];
        A_ws[off] = S;                     // entry state of chunk c
        S = fmaf(Ac, S, Bc);
    }
}

// ---------------------------------------------------------------------------
// Kernel 2c: replay the scan per (b, chunk) from its entry state; writes all
// Mv states and read[b,l,d] = sum_m w*Mv_pre.
// ---------------------------------------------------------------------------
__global__ __launch_bounds__(128) void k_scanC(
    const float* __restrict__ Sentry,     // == A_ws after k_scanB
    const float* __restrict__ w_ws, const float* __restrict__ e_ws,
    const float* __restrict__ a_ws,
    float* __restrict__ read_ws, float* __restrict__ out_Mv)
{
    const int b = blockIdx.x / NC;
    const int c = blockIdx.x % NC;
    const int d = threadIdx.x;

    float S[MM];
    const float* Sp = Sentry + ((size_t)b * NC + c) * MM * DD + d;
    float* outb = out_Mv + (size_t)b * (LL + 1) * MM * DD;
    #pragma unroll
    for (int m = 0; m < MM; ++m) S[m] = Sp[m * DD];

    if (c == 0) {
        #pragma unroll
        for (int m = 0; m < MM; ++m) outb[m * DD + d] = S[m];  // init state row
    }

    for (int l = c * LC; l < c * LC + LC; ++l) {
        const int gp = b * LL + l;
        const float e = e_ws[(size_t)gp * DD + d];
        const float a = a_ws[(size_t)gp * DD + d];
        const float* wp = w_ws + (size_t)gp * MM;
        float w_[MM];
        #pragma unroll
        for (int m = 0; m < MM; ++m) w_[m] = wp[m];

        float racc = 0.f;
        float* o = outb + (size_t)(l + 1) * MM * DD + d;
        #pragma unroll
        for (int m = 0; m < MM; ++m) {
            racc = fmaf(w_[m], S[m], racc);              // read uses pre-update state
            S[m] = fmaf(w_[m], fmaf(-S[m], e, a), S[m]); // S += w*(a - S*e)
            o[m * DD] = S[m];
        }
        read_ws[(size_t)gp * DD + d] = racc;
    }
}

// ---------------------------------------------------------------------------
// Kernel 3: f = tanh([read,k] @ f_W^T + f_b); p = sigmoid(f . p_W + p_b).
// One block = 16 positions, 128 threads.
// ---------------------------------------------------------------------------
__global__ __launch_bounds__(128) void k_fp(
    const int* __restrict__ q,
    const float* __restrict__ k_emb,
    const float* __restrict__ read_ws,
    const float* __restrict__ f_W, const float* __restrict__ f_b,
    const float* __restrict__ p_W, const float* __restrict__ p_b,
    float* __restrict__ out_p)
{
    __shared__ float cat[16][2 * DD];
    __shared__ float fv[16][DD];

    const int tid = threadIdx.x;
    const int p0  = blockIdx.x * 16;

    // stage [read, k] rows (256 floats each) into LDS
    #pragma unroll
    for (int rep = 0; rep < 8; ++rep) {
        int idx = rep * 128 + tid;        // 0..1023 = 16 pos x 64 float4
        int pos = idx >> 6;
        int c4  = idx & 63;
        int gp  = p0 + pos;
        float4 val;
        if (c4 < 32) val = *(const float4*)(read_ws + (size_t)gp * DD + c4 * 4);
        else         val = *(const float4*)(k_emb + (size_t)q[gp] * DD + (c4 - 32) * 4);
        *(float4*)(&cat[pos][c4 * 4]) = val;
    }
    __syncthreads();

    // f: thread i computes f[pos][i] for all 16 positions
    const int i = tid;
    float acc[16];
    const float fb = f_b[i];
    #pragma unroll
    for (int p = 0; p < 16; ++p) acc[p] = fb;

    const float4* fw = (const float4*)(f_W + (size_t)i * (2 * DD));
    #pragma unroll 2
    for (int j4 = 0; j4 < 64; ++j4) {
        float4 wv = fw[j4];
        #pragma unroll
        for (int p = 0; p < 16; ++p) {
            const float* cp = &cat[p][j4 * 4];
            acc[p] = fmaf(wv.x, cp[0], acc[p]);
            acc[p] = fmaf(wv.y, cp[1], acc[p]);
            acc[p] = fmaf(wv.z, cp[2], acc[p]);
            acc[p] = fmaf(wv.w, cp[3], acc[p]);
        }
    }
    #pragma unroll
    for (int p = 0; p < 16; ++p) fv[p][i] = tanhf(acc[p]);
    __syncthreads();

    // p: 16 positions x 8 lanes each
    const int pos = tid >> 3;
    const int l8  = tid & 7;
    float partial = 0.f;
    #pragma unroll
    for (int ii = l8; ii < DD; ii += 8)
        partial = fmaf(fv[pos][ii], p_W[ii], partial);
    partial += __shfl_down(partial, 4, 64);
    partial += __shfl_down(partial, 2, 64);
    partial += __shfl_down(partial, 1, 64);
    if (l8 == 0)
        out_p[p0 + pos] = 1.f / (1.f + expf(-(partial + p_b[0])));
}

// ---------------------------------------------------------------------------
extern "C" void kernel_launch(void* const* d_in, const int* in_sizes, int n_in,
                              void* d_out, int out_size, void* d_ws, size_t ws_size,
                              hipStream_t stream)
{
    const int*   q     = (const int*)d_in[0];
    const int*   r     = (const int*)d_in[1];
    const float* k_emb = (const float*)d_in[2];
    const float* v_emb = (const float*)d_in[3];
    const float* Mk    = (const float*)d_in[4];
    const float* Mv0   = (const float*)d_in[5];
    const float* f_W   = (const float*)d_in[6];
    const float* f_b   = (const float*)d_in[7];
    const float* p_W   = (const float*)d_in[8];
    const float* p_b   = (const float*)d_in[9];
    const float* e_W   = (const float*)d_in[10];
    const float* e_b   = (const float*)d_in[11];
    const float* a_W   = (const float*)d_in[12];
    const float* a_b   = (const float*)d_in[13];

    float* out_p  = (float*)d_out;           // [B,L]
    float* out_Mv = out_p + NPOS;            // [B,L+1,M,D]

    float* w_ws    = (float*)d_ws;                         // NPOS*MM
    float* e_ws    = w_ws + (size_t)NPOS * MM;             // NPOS*DD
    float* a_ws    = e_ws + (size_t)NPOS * DD;             // NPOS*DD
    float* read_ws = a_ws + (size_t)NPOS * DD;             // NPOS*DD
    float* A_ws    = read_ws + (size_t)NPOS * DD;          // B*NC*MM*DD
    float* B_ws    = A_ws + (size_t)BB * NC * MM * DD;     // B*NC*MM*DD

    hipLaunchKernelGGL(k_wea, dim3(NPOS / 16), dim3(256), 0, stream,
                       q, r, k_emb, v_emb, Mk, e_W, e_b, a_W, a_b,
                       w_ws, e_ws, a_ws);
    hipLaunchKernelGGL(k_scanA, dim3(BB * NC), dim3(128), 0, stream,
                       w_ws, e_ws, a_ws, A_ws, B_ws);
    hipLaunchKernelGGL(k_scanB, dim3((BB * MM * DD) / 256), dim3(256), 0, stream,
                       Mv0, A_ws, B_ws);
    hipLaunchKernelGGL(k_scanC, dim3(BB * NC), dim3(128), 0, stream,
                       A_ws, w_ws, e_ws, a_ws, read_ws, out_Mv);
    hipLaunchKernelGGL(k_fp, dim3(NPOS / 16), dim3(128), 0, stream,
                       q, k_emb, read_ws, f_W, f_b, p_W, p_b, out_p);
}

// Round 3
// 222.692 us; speedup vs baseline: 1.2771x; 1.0084x over previous
//
#include <hip/hip_runtime.h>
#include <math.h>

#define BB 64
#define LL 200
#define DD 128
#define MM 50
#define NQ 10000
#define NPOS (BB * LL)   // 12800
#define LC 20            // scan chunk length
#define NC 10            // number of chunks (LC*NC == LL)

// ---------------------------------------------------------------------------
// Kernel 1: gather k,v; compute w = softmax(k@Mk^T), e = sigmoid(v@e_W^T+e_b),
//           a = tanh(v@a_W^T+a_b) for all B*L positions.
// One block = 16 positions, 256 threads.
// ---------------------------------------------------------------------------
__global__ __launch_bounds__(256) void k_wea(
    const int* __restrict__ q, const int* __restrict__ r,
    const float* __restrict__ k_emb, const float* __restrict__ v_emb,
    const float* __restrict__ Mk,
    const float* __restrict__ e_W, const float* __restrict__ e_b,
    const float* __restrict__ a_W, const float* __restrict__ a_b,
    float* __restrict__ w_ws, float* __restrict__ e_ws, float* __restrict__ a_ws)
{
    __shared__ float k_lds[16][DD];
    __shared__ float v_lds[16][DD];
    __shared__ float lg[16][MM];

    const int tid = threadIdx.x;
    const int p0  = blockIdx.x * 16;

    // ---- stage k, v rows into LDS (float4-coalesced) ----
    #pragma unroll
    for (int rep = 0; rep < 2; ++rep) {
        int idx = rep * 256 + tid;        // 0..511
        int pos = idx >> 5;               // 16 positions x 32 float4
        int c4  = idx & 31;
        int gp  = p0 + pos;
        int qi  = q[gp];
        int xi  = qi + NQ * r[gp];
        float4 kv = *(const float4*)(k_emb + (size_t)qi * DD + c4 * 4);
        float4 vv = *(const float4*)(v_emb + (size_t)xi * DD + c4 * 4);
        *(float4*)(&k_lds[pos][c4 * 4]) = kv;
        *(float4*)(&v_lds[pos][c4 * 4]) = vv;
    }
    __syncthreads();

    // ---- logits: 16 pos x 50 m dots of length 128 ----
    for (int j = tid; j < 16 * MM; j += 256) {
        int pos = j / MM;
        int m   = j - pos * MM;
        const float* mk = Mk + m * DD;
        float acc = 0.f;
        #pragma unroll 4
        for (int jj = 0; jj < DD; ++jj)
            acc = fmaf(k_lds[pos][jj], mk[jj], acc);
        lg[pos][m] = acc;
    }
    __syncthreads();

    // ---- softmax over M=50, one thread per position ----
    if (tid < 16) {
        int pos = tid;
        float mx = -INFINITY;
        for (int m = 0; m < MM; ++m) mx = fmaxf(mx, lg[pos][m]);
        float s = 0.f;
        for (int m = 0; m < MM; ++m) {
            float e_ = expf(lg[pos][m] - mx);
            lg[pos][m] = e_;
            s += e_;
        }
        float inv = 1.f / s;
        float* wout = w_ws + (size_t)(p0 + pos) * MM;
        for (int m = 0; m < MM; ++m) wout[m] = lg[pos][m] * inv;
    }

    // ---- e, a: thread (i = tid&127) x (half = tid>>7 -> 8 positions) ----
    const int i    = tid & 127;
    const int half = tid >> 7;
    float acc_e[8], acc_a[8];
    const float eb = e_b[i];
    const float ab = a_b[i];
    #pragma unroll
    for (int p = 0; p < 8; ++p) { acc_e[p] = eb; acc_a[p] = ab; }

    const float4* ew = (const float4*)(e_W + (size_t)i * DD);
    const float4* aw = (const float4*)(a_W + (size_t)i * DD);
    #pragma unroll 4
    for (int j4 = 0; j4 < 32; ++j4) {
        float4 we = ew[j4];
        float4 wa = aw[j4];
        #pragma unroll
        for (int p = 0; p < 8; ++p) {
            const float* vp = &v_lds[half * 8 + p][j4 * 4];
            acc_e[p] = fmaf(we.x, vp[0], acc_e[p]);
            acc_e[p] = fmaf(we.y, vp[1], acc_e[p]);
            acc_e[p] = fmaf(we.z, vp[2], acc_e[p]);
            acc_e[p] = fmaf(we.w, vp[3], acc_e[p]);
            acc_a[p] = fmaf(wa.x, vp[0], acc_a[p]);
            acc_a[p] = fmaf(wa.y, vp[1], acc_a[p]);
            acc_a[p] = fmaf(wa.z, vp[2], acc_a[p]);
            acc_a[p] = fmaf(wa.w, vp[3], acc_a[p]);
        }
    }
    #pragma unroll
    for (int p = 0; p < 8; ++p) {
        int gp = p0 + half * 8 + p;
        e_ws[(size_t)gp * DD + i] = 1.f / (1.f + expf(-acc_e[p]));
        a_ws[(size_t)gp * DD + i] = tanhf(acc_a[p]);
    }
}

// ---------------------------------------------------------------------------
// Kernel 2a: per (b, chunk) affine composite S_out = A*S_in + B per (m,d).
// 512 threads = 4 groups of 128; group g owns ~13 of the 50 m-rows.
// w staged in LDS (one coalesced 1000-float copy), broadcast reads after.
// ---------------------------------------------------------------------------
__global__ __launch_bounds__(512) void k_scanA(
    const float* __restrict__ w_ws, const float* __restrict__ e_ws,
    const float* __restrict__ a_ws,
    float* __restrict__ A_ws, float* __restrict__ B_ws)
{
    __shared__ float w_lds[LC * MM];   // 4 KB

    const int b   = blockIdx.x / NC;
    const int c   = blockIdx.x % NC;
    const int tid = threadIdx.x;
    const int d   = tid & 127;
    const int g   = tid >> 7;
    int moff = g * 13; if (g == 3) moff = 38;
    const int mcnt = (g < 2) ? 13 : 12;

    const float* wsrc = w_ws + ((size_t)b * LL + c * LC) * MM;  // contiguous
    for (int idx = tid; idx < LC * MM; idx += 512) w_lds[idx] = wsrc[idx];
    __syncthreads();

    float A[13], Bv[13];
    #pragma unroll
    for (int mi = 0; mi < 13; ++mi) { A[mi] = 1.f; Bv[mi] = 0.f; }

    for (int ll = 0; ll < LC; ++ll) {
        const int gp = b * LL + c * LC + ll;
        const float e = e_ws[(size_t)gp * DD + d];
        const float a = a_ws[(size_t)gp * DD + d];
        const float* wl = w_lds + ll * MM + moff;
        #pragma unroll
        for (int mi = 0; mi < 13; ++mi) {
            if (mi < mcnt) {
                float w_ = wl[mi];
                float cc = fmaf(-w_, e, 1.f);
                A[mi] *= cc;
                Bv[mi] = fmaf(Bv[mi], cc, w_ * a);
            }
        }
    }

    float* Ao = A_ws + ((size_t)b * NC + c) * MM * DD + (size_t)moff * DD + d;
    float* Bo = B_ws + ((size_t)b * NC + c) * MM * DD + (size_t)moff * DD + d;
    #pragma unroll
    for (int mi = 0; mi < 13; ++mi) {
        if (mi < mcnt) { Ao[mi * DD] = A[mi]; Bo[mi * DD] = Bv[mi]; }
    }
}

// ---------------------------------------------------------------------------
// Kernel 2b: sequential composition over chunks; writes chunk ENTRY states
// in-place over A_ws. One thread per (b,m,d).
// ---------------------------------------------------------------------------
__global__ __launch_bounds__(256) void k_scanB(
    const float* __restrict__ Mv0,
    float* __restrict__ A_ws,            // in: A, out: Sentry
    const float* __restrict__ B_ws)
{
    const int g  = blockIdx.x * 256 + threadIdx.x;   // 0 .. B*M*D-1
    const int d  = g & (DD - 1);
    const int md = g >> 7;
    const int m  = md % MM;
    const int b  = md / MM;

    float S = Mv0[m * DD + d];
    const size_t base = ((size_t)b * NC * MM + m) * DD + d;  // +c*MM*DD per chunk
    #pragma unroll
    for (int c = 0; c < NC; ++c) {
        const size_t off = base + (size_t)c * MM * DD;
        const float Ac = A_ws[off];
        const float Bc = B_ws[off];
        A_ws[off] = S;                     // entry state of chunk c
        S = fmaf(Ac, S, Bc);
    }
}

// ---------------------------------------------------------------------------
// Kernel 2c: replay the scan per (b, chunk) from its entry state; writes all
// Mv states and read[b,l,d] = sum_m w*Mv_pre.
// 512 threads = 4 m-groups; read-reduce via parity-double-buffered LDS.
// ---------------------------------------------------------------------------
__global__ __launch_bounds__(512) void k_scanC(
    const float* __restrict__ Sentry,     // == A_ws after k_scanB
    const float* __restrict__ w_ws, const float* __restrict__ e_ws,
    const float* __restrict__ a_ws,
    float* __restrict__ read_ws, float* __restrict__ out_Mv)
{
    __shared__ float w_lds[LC * MM];      // 4 KB
    __shared__ float red[2][4][DD];       // 4 KB

    const int b   = blockIdx.x / NC;
    const int c   = blockIdx.x % NC;
    const int tid = threadIdx.x;
    const int d   = tid & 127;
    const int g   = tid >> 7;
    int moff = g * 13; if (g == 3) moff = 38;
    const int mcnt = (g < 2) ? 13 : 12;

    const float* wsrc = w_ws + ((size_t)b * LL + c * LC) * MM;
    for (int idx = tid; idx < LC * MM; idx += 512) w_lds[idx] = wsrc[idx];

    float S[13];
    const float* Sp = Sentry + ((size_t)b * NC + c) * MM * DD + (size_t)moff * DD + d;
    #pragma unroll
    for (int mi = 0; mi < 13; ++mi)
        if (mi < mcnt) S[mi] = Sp[mi * DD];

    float* outb = out_Mv + (size_t)b * (LL + 1) * MM * DD;
    if (c == 0) {
        #pragma unroll
        for (int mi = 0; mi < 13; ++mi)
            if (mi < mcnt) outb[(moff + mi) * DD + d] = S[mi];  // init state
    }
    __syncthreads();

    for (int ll = 0; ll < LC; ++ll) {
        const int l  = c * LC + ll;
        const int gp = b * LL + l;
        const float e = e_ws[(size_t)gp * DD + d];
        const float a = a_ws[(size_t)gp * DD + d];
        const float* wl = w_lds + ll * MM + moff;

        float racc = 0.f;
        float* o = outb + (size_t)(l + 1) * MM * DD + d;
        #pragma unroll
        for (int mi = 0; mi < 13; ++mi) {
            if (mi < mcnt) {
                float w_ = wl[mi];
                racc = fmaf(w_, S[mi], racc);               // read uses pre-update S
                S[mi] = fmaf(w_, fmaf(-S[mi], e, a), S[mi]); // S += w*(a - S*e)
                o[(moff + mi) * DD] = S[mi];
            }
        }
        red[ll & 1][g][d] = racc;
        __syncthreads();
        if (g == 0)
            read_ws[(size_t)gp * DD + d] =
                red[ll & 1][0][d] + red[ll & 1][1][d] +
                red[ll & 1][2][d] + red[ll & 1][3][d];
    }
}

// ---------------------------------------------------------------------------
// Kernel 3: f = tanh([read,k] @ f_W^T + f_b); p = sigmoid(f . p_W + p_b).
// One block = 16 positions, 128 threads.
// ---------------------------------------------------------------------------
__global__ __launch_bounds__(128) void k_fp(
    const int* __restrict__ q,
    const float* __restrict__ k_emb,
    const float* __restrict__ read_ws,
    const float* __restrict__ f_W, const float* __restrict__ f_b,
    const float* __restrict__ p_W, const float* __restrict__ p_b,
    float* __restrict__ out_p)
{
    __shared__ float cat[16][2 * DD];
    __shared__ float fv[16][DD];

    const int tid = threadIdx.x;
    const int p0  = blockIdx.x * 16;

    // stage [read, k] rows (256 floats each) into LDS
    #pragma unroll
    for (int rep = 0; rep < 8; ++rep) {
        int idx = rep * 128 + tid;        // 0..1023 = 16 pos x 64 float4
        int pos = idx >> 6;
        int c4  = idx & 63;
        int gp  = p0 + pos;
        float4 val;
        if (c4 < 32) val = *(const float4*)(read_ws + (size_t)gp * DD + c4 * 4);
        else         val = *(const float4*)(k_emb + (size_t)q[gp] * DD + (c4 - 32) * 4);
        *(float4*)(&cat[pos][c4 * 4]) = val;
    }
    __syncthreads();

    // f: thread i computes f[pos][i] for all 16 positions
    const int i = tid;
    float acc[16];
    const float fb = f_b[i];
    #pragma unroll
    for (int p = 0; p < 16; ++p) acc[p] = fb;

    const float4* fw = (const float4*)(f_W + (size_t)i * (2 * DD));
    #pragma unroll 2
    for (int j4 = 0; j4 < 64; ++j4) {
        float4 wv = fw[j4];
        #pragma unroll
        for (int p = 0; p < 16; ++p) {
            const float* cp = &cat[p][j4 * 4];
            acc[p] = fmaf(wv.x, cp[0], acc[p]);
            acc[p] = fmaf(wv.y, cp[1], acc[p]);
            acc[p] = fmaf(wv.z, cp[2], acc[p]);
            acc[p] = fmaf(wv.w, cp[3], acc[p]);
        }
    }
    #pragma unroll
    for (int p = 0; p < 16; ++p) fv[p][i] = tanhf(acc[p]);
    __syncthreads();

    // p: 16 positions x 8 lanes each
    const int pos = tid >> 3;
    const int l8  = tid & 7;
    float partial = 0.f;
    #pragma unroll
    for (int ii = l8; ii < DD; ii += 8)
        partial = fmaf(fv[pos][ii], p_W[ii], partial);
    partial += __shfl_down(partial, 4, 64);
    partial += __shfl_down(partial, 2, 64);
    partial += __shfl_down(partial, 1, 64);
    if (l8 == 0)
        out_p[p0 + pos] = 1.f / (1.f + expf(-(partial + p_b[0])));
}

// ---------------------------------------------------------------------------
extern "C" void kernel_launch(void* const* d_in, const int* in_sizes, int n_in,
                              void* d_out, int out_size, void* d_ws, size_t ws_size,
                              hipStream_t stream)
{
    const int*   q     = (const int*)d_in[0];
    const int*   r     = (const int*)d_in[1];
    const float* k_emb = (const float*)d_in[2];
    const float* v_emb = (const float*)d_in[3];
    const float* Mk    = (const float*)d_in[4];
    const float* Mv0   = (const float*)d_in[5];
    const float* f_W   = (const float*)d_in[6];
    const float* f_b   = (const float*)d_in[7];
    const float* p_W   = (const float*)d_in[8];
    const float* p_b   = (const float*)d_in[9];
    const float* e_W   = (const float*)d_in[10];
    const float* e_b   = (const float*)d_in[11];
    const float* a_W   = (const float*)d_in[12];
    const float* a_b   = (const float*)d_in[13];

    float* out_p  = (float*)d_out;           // [B,L]
    float* out_Mv = out_p + NPOS;            // [B,L+1,M,D]

    float* w_ws    = (float*)d_ws;                         // NPOS*MM
    float* e_ws    = w_ws + (size_t)NPOS * MM;             // NPOS*DD
    float* a_ws    = e_ws + (size_t)NPOS * DD;             // NPOS*DD
    float* read_ws = a_ws + (size_t)NPOS * DD;             // NPOS*DD
    float* A_ws    = read_ws + (size_t)NPOS * DD;          // B*NC*MM*DD
    float* B_ws    = A_ws + (size_t)BB * NC * MM * DD;     // B*NC*MM*DD

    hipLaunchKernelGGL(k_wea, dim3(NPOS / 16), dim3(256), 0, stream,
                       q, r, k_emb, v_emb, Mk, e_W, e_b, a_W, a_b,
                       w_ws, e_ws, a_ws);
    hipLaunchKernelGGL(k_scanA, dim3(BB * NC), dim3(512), 0, stream,
                       w_ws, e_ws, a_ws, A_ws, B_ws);
    hipLaunchKernelGGL(k_scanB, dim3((BB * MM * DD) / 256), dim3(256), 0, stream,
                       Mv0, A_ws, B_ws);
    hipLaunchKernelGGL(k_scanC, dim3(BB * NC), dim3(512), 0, stream,
                       A_ws, w_ws, e_ws, a_ws, read_ws, out_Mv);
    hipLaunchKernelGGL(k_fp, dim3(NPOS / 16), dim3(128), 0, stream,
                       q, k_emb, read_ws, f_W, f_b, p_W, p_b, out_p);
}